// Round 1
// baseline (130.228 us; speedup 1.0000x reference)
//
#include <hip/hip_runtime.h>
#include <hip/hip_bf16.h>
#include <cstdint>
#include <cstddef>

// Problem constants
#define B_    16
#define S_    1024
#define D_    512
#define P_    256
#define MAXS_ 2048

typedef unsigned short u16;
typedef unsigned int   u32;
typedef __bf16 bf16x8 __attribute__((ext_vector_type(8)));
typedef float  f32x4  __attribute__((ext_vector_type(4)));
typedef unsigned short u16x4 __attribute__((ext_vector_type(4)));
typedef unsigned short u16x8 __attribute__((ext_vector_type(8)));

__device__ __forceinline__ u16 f2bf(float f) {
  // round-to-nearest-even f32 -> bf16 (no NaN inputs expected)
  u32 u = __builtin_bit_cast(u32, f);
  u32 r = u + 0x7fffu + ((u >> 16) & 1u);
  return (u16)(r >> 16);
}

__device__ __forceinline__ void gld_lds16(const void* g, void* l) {
  __builtin_amdgcn_global_load_lds(
      (const __attribute__((address_space(1))) u32*)g,
      (__attribute__((address_space(3))) u32*)l, 16, 0, 0);
}

// ---------------------------------------------------------------------------
// K5: zero-fill out[:, S:2S, :]  (d_out poisoned once; must write every call)
// ---------------------------------------------------------------------------
__global__ void zero_tail_kernel(float4* __restrict__ out) {
  const long per = (long)S_ * P_ / 4;          // 65536 float4 per batch tail
  const long tot = (long)B_ * per;             // 1,048,576
  long stride = (long)gridDim.x * blockDim.x;
  for (long i = (long)blockIdx.x * blockDim.x + threadIdx.x; i < tot; i += stride) {
    long b = i >> 16;          // per == 2^16
    long r = i & 65535;
    out[b * ((long)MAXS_ * P_ / 4) + per + r] = make_float4(0.f, 0.f, 0.f, 0.f);
  }
}

// ---------------------------------------------------------------------------
// K0a: fp32 -> bf16 linear convert (data, W)
// ---------------------------------------------------------------------------
__global__ void convert_bf16_kernel(const float* __restrict__ src, u16* __restrict__ dst, long n4) {
  long stride = (long)gridDim.x * blockDim.x;
  for (long i = (long)blockIdx.x * blockDim.x + threadIdx.x; i < n4; i += stride) {
    float4 v = ((const float4*)src)[i];
    u16x4 o;
    o[0] = f2bf(v.x); o[1] = f2bf(v.y); o[2] = f2bf(v.z); o[3] = f2bf(v.w);
    ((u16x4*)dst)[i] = o;
  }
}

// ---------------------------------------------------------------------------
// K0b: data [B][S][D] f32  ->  dataBT [B][D][S] bf16  (tiled transpose)
// ---------------------------------------------------------------------------
__global__ __launch_bounds__(256) void transpose_bf16_kernel(
    const float* __restrict__ src, u16* __restrict__ dst) {
  __shared__ u16 tl[64][72];   // [t][d], padded
  const int b  = blockIdx.z;
  const int t0 = blockIdx.y * 64;
  const int d0 = blockIdx.x * 64;
  const float* s = src + (size_t)b * S_ * D_;
  u16* o = dst + (size_t)b * S_ * D_;
  const int tid = threadIdx.x;

  #pragma unroll
  for (int p = 0; p < 4; ++p) {
    int tr = p * 16 + (tid >> 4);
    int dc = (tid & 15) << 2;
    float4 v = *(const float4*)&s[(size_t)(t0 + tr) * D_ + d0 + dc];
    tl[tr][dc + 0] = f2bf(v.x);
    tl[tr][dc + 1] = f2bf(v.y);
    tl[tr][dc + 2] = f2bf(v.z);
    tl[tr][dc + 3] = f2bf(v.w);
  }
  __syncthreads();
  #pragma unroll
  for (int p = 0; p < 2; ++p) {
    int dr = p * 32 + (tid >> 3);
    int tc = (tid & 7) << 3;
    u16x8 ov;
    #pragma unroll
    for (int j = 0; j < 8; ++j) ov[j] = tl[tc + j][dr];
    *(u16x8*)&o[(size_t)(d0 + dr) * S_ + t0 + tc] = ov;
  }
}

// ---------------------------------------------------------------------------
// NT GEMM, m97 structure: C[MxN] = A[MxK] * B[NxK]^T
//   128x128 tile, BK=64, 4 waves (2x2), each wave 64x64 via 4x4 frags of
//   mfma_f32_16x16x32_bf16. Row stride of A and B == K. Batched via blockIdx.z.
// EPI: 0 = f32 out * scale (scores); 1 = bf16 out (attn); 2 = f32 out + bias.
// ---------------------------------------------------------------------------
template<int EPI>
__global__ __launch_bounds__(256) void gemm_nt(
    const u16* __restrict__ A, const u16* __restrict__ Bmat,
    void* __restrict__ C, const float* __restrict__ bias,
    int K, long sAb, long sBb, long sCb, int LDC, float scale) {
  __shared__ u16 Asm[128 * 64];
  __shared__ u16 Bsm[128 * 64];

  const int tid  = threadIdx.x;
  const int lane = tid & 63;
  const int wv   = tid >> 6;
  const int wm   = wv >> 1, wn = wv & 1;    // 2x2 waves over 128x128
  const int lr   = lane & 15;               // fragment row (A) / col (C)
  const int lk   = (lane >> 4) << 3;        // k-offset base within 32

  const int bz = blockIdx.z;
  const int I0 = blockIdx.y * 128;
  const int J0 = blockIdx.x * 128;

  A    += (long)bz * sAb;
  Bmat += (long)bz * sBb;

  const int rs = tid >> 3;         // 0..31: row within a 32-row staging group
  const int cc = (tid & 7) << 3;   // 0..56: bf16 col of the 16B chunk

  f32x4 acc[4][4] = {};

  for (int k0 = 0; k0 < K; k0 += 64) {
    #pragma unroll
    for (int it = 0; it < 4; ++it) {
      int r = it * 32 + rs;
      gld_lds16(A + (size_t)(I0 + r) * K + k0 + cc, &Asm[r * 64 + cc]);
    }
    #pragma unroll
    for (int it = 0; it < 4; ++it) {
      int r = it * 32 + rs;
      gld_lds16(Bmat + (size_t)(J0 + r) * K + k0 + cc, &Bsm[r * 64 + cc]);
    }
    __syncthreads();   // drains vmcnt(0) before barrier
    #pragma unroll
    for (int kk = 0; kk < 2; ++kk) {
      bf16x8 af[4], bfv[4];
      #pragma unroll
      for (int m = 0; m < 4; ++m)
        af[m] = *(const bf16x8*)&Asm[(wm * 64 + m * 16 + lr) * 64 + kk * 32 + lk];
      #pragma unroll
      for (int n = 0; n < 4; ++n)
        bfv[n] = *(const bf16x8*)&Bsm[(wn * 64 + n * 16 + lr) * 64 + kk * 32 + lk];
      #pragma unroll
      for (int m = 0; m < 4; ++m)
        #pragma unroll
        for (int n = 0; n < 4; ++n)
          acc[m][n] = __builtin_amdgcn_mfma_f32_16x16x32_bf16(af[m], bfv[n], acc[m][n], 0, 0, 0);
    }
    __syncthreads();
  }

  // Epilogue. C/D frag layout: col = lane&15, row = (lane>>4)*4 + reg.
  const int row0 = I0 + wm * 64;
  const int col0 = J0 + wn * 64;
  #pragma unroll
  for (int m = 0; m < 4; ++m) {
    #pragma unroll
    for (int i = 0; i < 4; ++i) {
      int r = row0 + m * 16 + ((lane >> 4) << 2) + i;
      #pragma unroll
      for (int n = 0; n < 4; ++n) {
        int c = col0 + n * 16 + lr;
        float v = acc[m][n][i];
        long off = (long)bz * sCb + (size_t)r * LDC + c;
        if constexpr (EPI == 0) {
          ((float*)C)[off] = v * scale;
        } else if constexpr (EPI == 1) {
          ((u16*)C)[off] = f2bf(v);
        } else {
          ((float*)C)[off] = v + bias[c];
        }
      }
    }
  }
}

// ---------------------------------------------------------------------------
// K2: row softmax. scores [16384][1024] f32 -> prob bf16. One wave per row.
// ---------------------------------------------------------------------------
__global__ __launch_bounds__(256) void softmax_kernel(
    const float* __restrict__ scores, u16* __restrict__ prob) {
  const int lane = threadIdx.x & 63;
  const int wv   = threadIdx.x >> 6;
  const long row = (long)blockIdx.x * 4 + wv;
  const float* src = scores + row * S_;

  float4 v[4];
  #pragma unroll
  for (int c = 0; c < 4; ++c)
    v[c] = *(const float4*)&src[c * 256 + lane * 4];

  float mx = -3.4e38f;
  #pragma unroll
  for (int c = 0; c < 4; ++c)
    mx = fmaxf(mx, fmaxf(fmaxf(v[c].x, v[c].y), fmaxf(v[c].z, v[c].w)));
  #pragma unroll
  for (int off = 32; off > 0; off >>= 1)
    mx = fmaxf(mx, __shfl_xor(mx, off));

  const float l2e = 1.4426950408889634f;
  float e[16];
  float sum = 0.f;
  #pragma unroll
  for (int c = 0; c < 4; ++c) {
    e[c * 4 + 0] = exp2f((v[c].x - mx) * l2e);
    e[c * 4 + 1] = exp2f((v[c].y - mx) * l2e);
    e[c * 4 + 2] = exp2f((v[c].z - mx) * l2e);
    e[c * 4 + 3] = exp2f((v[c].w - mx) * l2e);
    sum += e[c * 4 + 0] + e[c * 4 + 1] + e[c * 4 + 2] + e[c * 4 + 3];
  }
  #pragma unroll
  for (int off = 32; off > 0; off >>= 1)
    sum += __shfl_xor(sum, off);
  const float inv = 1.f / sum;

  #pragma unroll
  for (int c = 0; c < 4; ++c) {
    u16x4 o;
    #pragma unroll
    for (int j = 0; j < 4; ++j) o[j] = f2bf(e[c * 4 + j] * inv);
    *(u16x4*)&prob[row * S_ + c * 256 + lane * 4] = o;
  }
}

// ---------------------------------------------------------------------------
extern "C" void kernel_launch(void* const* d_in, const int* in_sizes, int n_in,
                              void* d_out, int out_size, void* d_ws, size_t ws_size,
                              hipStream_t stream) {
  const float* data = (const float*)d_in[0];   // [16][1024][512]
  const float* W    = (const float*)d_in[1];   // [256][512]
  const float* bias = (const float*)d_in[2];   // [256]
  float* out = (float*)d_out;                  // [16][2048][256]
  char*  ws  = (char*)d_ws;

  const size_t MB = 1024 * 1024;
  u16*   dataB  = (u16*)(ws);                    // 16 MB  [B][S][D] bf16
  u16*   dataBT = (u16*)(ws + 16 * MB);          // 16 MB  [B][D][S] bf16
  u16*   Wb     = (u16*)(ws + 32 * MB);          // 256 KB [P][D] bf16
  float* scores = (float*)(ws + 33 * MB);        // 64 MB  [B][S][S] f32
  u16*   prob   = (u16*)(ws + 97 * MB);          // 32 MB  [B][S][S] bf16
  u16*   attnB  = (u16*)(ws + 129 * MB);         // 16 MB  [B][S][D] bf16

  const float scale = 0.04419417382415922f;      // 1/sqrt(512)

  zero_tail_kernel<<<2048, 256, 0, stream>>>((float4*)out);
  convert_bf16_kernel<<<2048, 256, 0, stream>>>(data, dataB, (long)B_ * S_ * D_ / 4);
  convert_bf16_kernel<<<64, 256, 0, stream>>>(W, Wb, (long)P_ * D_ / 4);
  transpose_bf16_kernel<<<dim3(8, 16, 16), 256, 0, stream>>>(data, dataBT);

  // scores[b] = scale * dataB[b] (1024x512) @ dataB[b]^T  -> f32 [1024][1024]
  gemm_nt<0><<<dim3(8, 8, 16), 256, 0, stream>>>(
      dataB, dataB, (void*)scores, nullptr,
      512, (long)S_ * D_, (long)S_ * D_, (long)S_ * S_, S_, scale);

  softmax_kernel<<<4096, 256, 0, stream>>>(scores, prob);

  // attn[b] = prob[b] (1024x1024) @ dataBT[b]^T (i.e. V) -> bf16 [1024][512]
  gemm_nt<1><<<dim3(4, 8, 16), 256, 0, stream>>>(
      prob, dataBT, (void*)attnB, nullptr,
      1024, (long)S_ * S_, (long)S_ * D_, (long)S_ * D_, D_, 0.f);

  // out[b][:S] = attn[b] (1024x512) @ W^T + bias -> f32 rows of [2048][256]
  gemm_nt<2><<<dim3(2, 8, 16), 256, 0, stream>>>(
      attnB, Wb, (void*)out, bias,
      512, (long)S_ * D_, 0L, (long)MAXS_ * P_, P_, 0.f);
}

// Round 2
// 105.433 us; speedup vs baseline: 1.2352x; 1.2352x over previous
//
#include <hip/hip_runtime.h>
#include <cstdint>
#include <cstddef>

// Problem constants
#define B_    16
#define S_    1024
#define D_    512
#define P_    256
#define MAXS_ 2048

typedef unsigned short u16;
typedef unsigned int   u32;
typedef _Float16 f16;
typedef _Float16 f16x8 __attribute__((ext_vector_type(8)));
typedef float  f32x4  __attribute__((ext_vector_type(4)));
typedef unsigned short u16x4 __attribute__((ext_vector_type(4)));
typedef unsigned short u16x8 __attribute__((ext_vector_type(8)));

__device__ __forceinline__ void gld_lds16(const void* g, void* l) {
  __builtin_amdgcn_global_load_lds(
      (const __attribute__((address_space(1))) u32*)g,
      (__attribute__((address_space(3))) u32*)l, 16, 0, 0);
}

__device__ __forceinline__ u16 f2h(float f) {
  return __builtin_bit_cast(u16, (f16)f);
}
__device__ __forceinline__ float h2f(u16 h) {
  return (float)__builtin_bit_cast(f16, h);
}

// ---------------------------------------------------------------------------
// zero-fill out[:, S:2S, :]  (d_out poisoned once; must write every call)
// ---------------------------------------------------------------------------
__global__ void zero_tail_kernel(float4* __restrict__ out) {
  const long per = (long)S_ * P_ / 4;          // 65536 float4 per batch tail
  const long tot = (long)B_ * per;
  long stride = (long)gridDim.x * blockDim.x;
  for (long i = (long)blockIdx.x * blockDim.x + threadIdx.x; i < tot; i += stride) {
    long b = i >> 16;          // per == 2^16
    long r = i & 65535;
    out[b * ((long)MAXS_ * P_ / 4) + per + r] = make_float4(0.f, 0.f, 0.f, 0.f);
  }
}

// ---------------------------------------------------------------------------
// prep: data f32 [B][S][D] -> dataH f16 [B][S][D] AND dataHT f16 [B][D][S]
// (single read of the 64 MB input; fused convert + transpose)
// ---------------------------------------------------------------------------
__global__ __launch_bounds__(256) void prep_kernel(
    const float* __restrict__ src, u16* __restrict__ dstR, u16* __restrict__ dstT) {
  __shared__ u16 tl[64][72];   // padded
  const int b  = blockIdx.z;
  const int t0 = blockIdx.y * 64;
  const int d0 = blockIdx.x * 64;
  const float* s = src + (size_t)b * S_ * D_;
  u16* oR = dstR + (size_t)b * S_ * D_;
  u16* oT = dstT + (size_t)b * S_ * D_;
  const int tid = threadIdx.x;

  #pragma unroll
  for (int p = 0; p < 4; ++p) {
    int tr = p * 16 + (tid >> 4);
    int dc = (tid & 15) << 2;
    float4 v = *(const float4*)&s[(size_t)(t0 + tr) * D_ + d0 + dc];
    u16x4 h;
    h[0] = f2h(v.x); h[1] = f2h(v.y); h[2] = f2h(v.z); h[3] = f2h(v.w);
    *(u16x4*)&oR[(size_t)(t0 + tr) * D_ + d0 + dc] = h;
    tl[tr][dc + 0] = h[0]; tl[tr][dc + 1] = h[1];
    tl[tr][dc + 2] = h[2]; tl[tr][dc + 3] = h[3];
  }
  __syncthreads();
  #pragma unroll
  for (int p = 0; p < 2; ++p) {
    int dr = p * 32 + (tid >> 3);
    int tc = (tid & 7) << 3;
    u16x8 ov;
    #pragma unroll
    for (int j = 0; j < 8; ++j) ov[j] = tl[tc + j][dr];
    *(u16x8*)&oT[(size_t)(d0 + dr) * S_ + t0 + tc] = ov;
  }
}

// ---------------------------------------------------------------------------
// W f32 -> f16
// ---------------------------------------------------------------------------
__global__ void convert_f16_kernel(const float* __restrict__ src, u16* __restrict__ dst, long n4) {
  long stride = (long)gridDim.x * blockDim.x;
  for (long i = (long)blockIdx.x * blockDim.x + threadIdx.x; i < n4; i += stride) {
    float4 v = ((const float4*)src)[i];
    u16x4 o;
    o[0] = f2h(v.x); o[1] = f2h(v.y); o[2] = f2h(v.z); o[3] = f2h(v.w);
    ((u16x4*)dst)[i] = o;
  }
}

// ---------------------------------------------------------------------------
// Deep-pipelined NT GEMM: C[MxN] = A[MxK] * B[NxK]^T, fp16 in, fp32 acc.
//   BM=256, BN=128, BK=64. 8 waves as 4M x 2N -> wave tile 64x64 (4x4 frags
//   of mfma_f32_16x16x32_f16). 3 LDS K-tile buffers (48 KB each, 144 KB
//   dynamic LDS) -> staging runs 2 tiles ahead; counted s_waitcnt vmcnt(6)
//   at the single per-tile barrier (never 0 in the main loop). T2 XOR
//   swizzle (chunk ^= row&7) applied on the pre-swizzled GLOBAL source
//   (gld_lds writes linearly) and on the ds_read address.
// Per thread per K-tile: 6 gld_lds16 (A:4, B:2). ld(A)=ld(B)=K.
// EPI: 0 = f16 out * scale; 1 = f16 out; 2 = f32 out + bias.
// ---------------------------------------------------------------------------
template<int EPI, int KK>
__global__ __launch_bounds__(512, 2) void gemm_pipe(
    const u16* __restrict__ A, const u16* __restrict__ Bm,
    void* __restrict__ C, const float* __restrict__ bias,
    long sAb, long sBb, long sCb, int LDC, float scale) {
  constexpr int NT = KK / 64;
  extern __shared__ __align__(16) char smem[];   // 3 * 49152 bytes

  const int tid  = threadIdx.x;
  const int lane = tid & 63;
  const int w    = tid >> 6;
  const int wm   = w >> 1;         // 0..3
  const int wn   = w & 1;          // 0..1
  const int lr   = lane & 15;
  const int hi   = lane >> 4;      // 0..3 (16B chunk within K=32 fragment)

  const int bz = blockIdx.z;
  const int I0 = blockIdx.y * 256;
  const int J0 = blockIdx.x * 128;
  const u16* Ab = A  + (long)bz * sAb;
  const u16* Bb = Bm + (long)bz * sBb;

  // stage one half of K-tile t into buffer `buf` (part = 0/1; 3 loads each)
  auto stage = [&](int buf, int k0, int part) {
    char* lA = smem + buf * 49152;
    char* lB = lA + 32768;
    #pragma unroll
    for (int qq = 0; qq < 2; ++qq) {
      int cid = (part * 2 + qq) * 512 + tid;       // A: 2048 chunks
      int row = cid >> 3;
      int c   = (cid & 7) ^ (row & 7);             // inverse-swizzled source
      gld_lds16(Ab + (size_t)(I0 + row) * KK + k0 + c * 8, lA + cid * 16);
    }
    {
      int cid = part * 512 + tid;                  // B: 1024 chunks
      int row = cid >> 3;
      int c   = (cid & 7) ^ (row & 7);
      gld_lds16(Bb + (size_t)(J0 + row) * KK + k0 + c * 8, lB + cid * 16);
    }
  };

  f32x4 acc[4][4] = {};

  // prologue: tiles 0 and 1 fully issued (12 loads outstanding)
  stage(0, 0, 0);  stage(0, 0, 1);
  stage(1, 64, 0); stage(1, 64, 1);

  int bR = 0;
  for (int t = 0; t < NT; ++t) {
    const char* lA = smem + bR * 49152;
    const char* lB = lA + 32768;
    int bS = bR + 2; if (bS >= 3) bS -= 3;

    // tile t must be landed. FIFO: [t (6), t+1 (6)] -> wait to 6 keeps t+1
    // in flight. Last iter: only t outstanding -> drain.
    if (t == NT - 1) asm volatile("s_waitcnt vmcnt(0)" ::: "memory");
    else             asm volatile("s_waitcnt vmcnt(6)" ::: "memory");
    __builtin_amdgcn_s_barrier();
    __builtin_amdgcn_sched_barrier(0);

    #pragma unroll
    for (int kk = 0; kk < 2; ++kk) {
      if (t + 2 < NT) stage(bS, (t + 2) * 64, kk);   // prefetch 2 tiles ahead
      f16x8 af[4], bf[4];
      #pragma unroll
      for (int m = 0; m < 4; ++m) {
        int row = wm * 64 + m * 16 + lr;
        int cp  = (kk * 4 + hi) ^ (row & 7);
        af[m] = *(const f16x8*)(lA + ((row * 8 + cp) << 4));
      }
      #pragma unroll
      for (int n = 0; n < 4; ++n) {
        int row = wn * 64 + n * 16 + lr;
        int cp  = (kk * 4 + hi) ^ (row & 7);
        bf[n] = *(const f16x8*)(lB + ((row * 8 + cp) << 4));
      }
      __builtin_amdgcn_s_setprio(1);
      #pragma unroll
      for (int m = 0; m < 4; ++m)
        #pragma unroll
        for (int n = 0; n < 4; ++n)
          acc[m][n] = __builtin_amdgcn_mfma_f32_16x16x32_f16(af[m], bf[n], acc[m][n], 0, 0, 0);
      __builtin_amdgcn_s_setprio(0);
    }
    __builtin_amdgcn_sched_barrier(0);
    bR = (bR + 1 == 3) ? 0 : bR + 1;
  }

  // epilogue. C/D frag layout: col = lane&15, row = (lane>>4)*4 + reg.
  const int row0 = I0 + wm * 64;
  const int col0 = J0 + wn * 64;
  float bv[4];
  if constexpr (EPI == 2) {
    #pragma unroll
    for (int n = 0; n < 4; ++n) bv[n] = bias[col0 + n * 16 + lr];
  }
  #pragma unroll
  for (int m = 0; m < 4; ++m) {
    #pragma unroll
    for (int i = 0; i < 4; ++i) {
      int r = row0 + m * 16 + (hi << 2) + i;
      #pragma unroll
      for (int n = 0; n < 4; ++n) {
        int c = col0 + n * 16 + lr;
        float v = acc[m][n][i];
        long off = (long)bz * sCb + (size_t)r * LDC + c;
        if constexpr (EPI == 0) {
          ((u16*)C)[off] = f2h(v * scale);
        } else if constexpr (EPI == 1) {
          ((u16*)C)[off] = f2h(v);
        } else {
          ((float*)C)[off] = v + bv[n];
        }
      }
    }
  }
}

// ---------------------------------------------------------------------------
// row softmax: scores [16384][1024] f16 -> prob f16. One wave per row.
// ---------------------------------------------------------------------------
__global__ __launch_bounds__(256) void softmax_kernel(
    const u16* __restrict__ scores, u16* __restrict__ prob) {
  const int lane = threadIdx.x & 63;
  const int wv   = threadIdx.x >> 6;
  const long row = (long)blockIdx.x * 4 + wv;
  const u16* src = scores + row * S_;

  u16x8 a0 = *(const u16x8*)&src[lane * 16];
  u16x8 a1 = *(const u16x8*)&src[lane * 16 + 8];
  float v[16];
  #pragma unroll
  for (int j = 0; j < 8; ++j) { v[j] = h2f(a0[j]); v[8 + j] = h2f(a1[j]); }

  float mx = -3.4e38f;
  #pragma unroll
  for (int j = 0; j < 16; ++j) mx = fmaxf(mx, v[j]);
  #pragma unroll
  for (int off = 32; off > 0; off >>= 1)
    mx = fmaxf(mx, __shfl_xor(mx, off));

  const float l2e = 1.4426950408889634f;
  float sum = 0.f;
  #pragma unroll
  for (int j = 0; j < 16; ++j) { v[j] = exp2f((v[j] - mx) * l2e); sum += v[j]; }
  #pragma unroll
  for (int off = 32; off > 0; off >>= 1)
    sum += __shfl_xor(sum, off);
  const float inv = 1.f / sum;

  u16x8 o0, o1;
  #pragma unroll
  for (int j = 0; j < 8; ++j) { o0[j] = f2h(v[j] * inv); o1[j] = f2h(v[8 + j] * inv); }
  *(u16x8*)&prob[row * S_ + lane * 16]     = o0;
  *(u16x8*)&prob[row * S_ + lane * 16 + 8] = o1;
}

// ---------------------------------------------------------------------------
extern "C" void kernel_launch(void* const* d_in, const int* in_sizes, int n_in,
                              void* d_out, int out_size, void* d_ws, size_t ws_size,
                              hipStream_t stream) {
  const float* data = (const float*)d_in[0];   // [16][1024][512]
  const float* W    = (const float*)d_in[1];   // [256][512]
  const float* bias = (const float*)d_in[2];   // [256]
  float* out = (float*)d_out;                  // [16][2048][256]
  char*  ws  = (char*)d_ws;

  const size_t MB = 1024 * 1024;
  u16* dataH  = (u16*)(ws);                    // 16 MB  [B][S][D] f16
  u16* dataHT = (u16*)(ws + 16 * MB);          // 16 MB  [B][D][S] f16
  u16* Wh     = (u16*)(ws + 32 * MB);          // 256 KB [P][D] f16
  u16* scoresH= (u16*)(ws + 33 * MB);          // 32 MB  [B][S][S] f16
  u16* probH  = (u16*)(ws + 65 * MB);          // 32 MB  [B][S][S] f16
  u16* attnH  = (u16*)(ws + 97 * MB);          // 16 MB  [B][S][D] f16

  const float scale = 0.04419417382415922f;    // 1/sqrt(512)
  const int   SMEM  = 3 * 49152;               // 144 KB

  hipFuncSetAttribute((const void*)gemm_pipe<0, 512>,
                      hipFuncAttributeMaxDynamicSharedMemorySize, SMEM);
  hipFuncSetAttribute((const void*)gemm_pipe<1, 1024>,
                      hipFuncAttributeMaxDynamicSharedMemorySize, SMEM);
  hipFuncSetAttribute((const void*)gemm_pipe<2, 512>,
                      hipFuncAttributeMaxDynamicSharedMemorySize, SMEM);

  zero_tail_kernel<<<2048, 256, 0, stream>>>((float4*)out);
  prep_kernel<<<dim3(8, 16, 16), 256, 0, stream>>>(data, dataH, dataHT);
  convert_f16_kernel<<<128, 256, 0, stream>>>(W, Wh, (long)P_ * D_ / 4);

  // scores[b] = scale * dataH[b] @ dataH[b]^T   [1024x1024] f16
  gemm_pipe<0, 512><<<dim3(8, 4, 16), 512, SMEM, stream>>>(
      dataH, dataH, (void*)scoresH, nullptr,
      (long)S_ * D_, (long)S_ * D_, (long)S_ * S_, S_, scale);

  softmax_kernel<<<4096, 256, 0, stream>>>(scoresH, probH);

  // attn[b] = prob[b] @ dataHT[b]^T            [1024x512] f16
  gemm_pipe<1, 1024><<<dim3(4, 4, 16), 512, SMEM, stream>>>(
      probH, dataHT, (void*)attnH, nullptr,
      (long)S_ * S_, (long)S_ * D_, (long)S_ * D_, D_, 0.f);

  // out[b][:S] = attn[b] @ W^T + bias          [1024x256] f32
  gemm_pipe<2, 512><<<dim3(2, 4, 16), 512, SMEM, stream>>>(
      attnH, Wh, (void*)out, bias,
      (long)S_ * D_, 0L, (long)MAXS_ * P_, P_, 0.f);
}

// Round 3
// 92.703 us; speedup vs baseline: 1.4048x; 1.1373x over previous
//
#include <hip/hip_runtime.h>
#include <cstdint>
#include <cstddef>

// Problem constants
#define B_    16
#define S_    1024
#define D_    512
#define P_    256
#define MAXS_ 2048

typedef unsigned short u16;
typedef unsigned int   u32;
typedef _Float16 f16;
typedef _Float16 f16x8 __attribute__((ext_vector_type(8)));
typedef float  f32x4  __attribute__((ext_vector_type(4)));
typedef unsigned short u16x4 __attribute__((ext_vector_type(4)));
typedef unsigned short u16x8 __attribute__((ext_vector_type(8)));

__device__ __forceinline__ void gld_lds16(const void* g, void* l) {
  __builtin_amdgcn_global_load_lds(
      (const __attribute__((address_space(1))) u32*)g,
      (__attribute__((address_space(3))) u32*)l, 16, 0, 0);
}

__device__ __forceinline__ u16 f2h(float f) {
  return __builtin_bit_cast(u16, (f16)f);
}
__device__ __forceinline__ float h2f(u16 h) {
  return (float)__builtin_bit_cast(f16, h);
}

template<int N> __device__ __forceinline__ void waitvm() {
  if constexpr (N == 0)       asm volatile("s_waitcnt vmcnt(0)" ::: "memory");
  else if constexpr (N == 8)  asm volatile("s_waitcnt vmcnt(8)" ::: "memory");
  else if constexpr (N == 20) asm volatile("s_waitcnt vmcnt(20)" ::: "memory");
  else static_assert(N != N, "unsupported vmcnt literal");
}

// ---------------------------------------------------------------------------
// f32 -> f16 convert (data, W)
// ---------------------------------------------------------------------------
__global__ void convert_f16_kernel(const float* __restrict__ src, u16* __restrict__ dst, long n4) {
  long stride = (long)gridDim.x * blockDim.x;
  for (long i = (long)blockIdx.x * blockDim.x + threadIdx.x; i < n4; i += stride) {
    float4 v = ((const float4*)src)[i];
    u16x4 o;
    o[0] = f2h(v.x); o[1] = f2h(v.y); o[2] = f2h(v.z); o[3] = f2h(v.w);
    ((u16x4*)dst)[i] = o;
  }
}

// ---------------------------------------------------------------------------
// Parameterized deep-pipe NT GEMM: C[MxN] = A[MxK]*B[NxK]^T, f16 in, f32 acc.
//   BK=64. 2 LDS buffers, counted vmcnt(L) (never 0 in main loop), two
//   barriers per K-tile. XOR swizzle chunk^=(row&7) applied on the GLOBAL
//   source (gld_lds dest stays linear, rule #21) and on the ds_read address.
//   Waves arranged WMS x WNS; wave tile (MF*16) x (NF*16) with MF*NF = 32
//   (128 VGPR acc) so per-tile LDS reads (24 b128 ~ 288cy) < MFMA (64 ~ 310cy)
//   -> MFMA-bound, unlike round-2's 64x64 wave tile (LDS-bound 1.24x).
// EPI: 0 = f16 out * scale; 1 = f16 out; 2 = f32 out + bias, and grid-y
//   blocks with I0 >= S_ only zero-fill out rows (folds zero_tail in).
// ---------------------------------------------------------------------------
template<int EPI, int KK, int BM, int BN, int NW, int WNS, int MINW>
__global__ __launch_bounds__(NW * 64, MINW) void gemm_pipe(
    const u16* __restrict__ A, const u16* __restrict__ Bm,
    void* __restrict__ C, const float* __restrict__ bias,
    long sAb, long sBb, long sCb, int LDC, float scale) {
  constexpr int T   = NW * 64;
  constexpr int WMS = NW / WNS;
  constexpr int MF  = BM / (WMS * 16);
  constexpr int NF  = BN / (WNS * 16);
  constexpr int LA  = BM * 8 / T;       // 16B chunks per thread (A)
  constexpr int LB  = BN * 8 / T;       // 16B chunks per thread (B)
  constexpr int L   = LA + LB;
  constexpr int SZ  = (BM + BN) * 128;  // bytes per LDS buffer (BK=64 f16)
  constexpr int NT  = KK / 64;
  static_assert(MF * NF == 32, "wave tile must be 32 frags");

  extern __shared__ __align__(16) char smem[];   // 2 * SZ

  const int tid  = threadIdx.x;
  const int lane = tid & 63;
  const int w    = tid >> 6;
  const int wm   = w / WNS;
  const int wn   = w % WNS;
  const int lr   = lane & 15;
  const int hi   = lane >> 4;      // 16B chunk within K=32 fragment

  const int bz = blockIdx.z;
  const int I0 = blockIdx.y * BM;
  const int J0 = blockIdx.x * BN;

  if constexpr (EPI == 2) {
    // tail blocks: rows S_..2S_-1 are hard zeros in the reference output
    if (I0 >= S_) {
      float4* o = (float4*)C + ((long)bz * sCb + (size_t)I0 * LDC) / 4;
      const int n4 = BM * LDC / 4;
      for (int i = tid; i < n4; i += T) o[i] = make_float4(0.f, 0.f, 0.f, 0.f);
      return;
    }
  }

  const u16* Ab = A  + (long)bz * sAb;
  const u16* Bb = Bm + (long)bz * sBb;

  auto stage = [&](int buf, int k0) {
    char* sA = smem + buf * SZ;
    char* sB = sA + BM * 128;
    #pragma unroll
    for (int i = 0; i < LA; ++i) {
      int cid = i * T + tid;
      int row = cid >> 3;
      int c   = (cid & 7) ^ (row & 7);      // inverse-swizzled global source
      gld_lds16(Ab + (size_t)(I0 + row) * KK + k0 + c * 8, sA + cid * 16);
    }
    #pragma unroll
    for (int i = 0; i < LB; ++i) {
      int cid = i * T + tid;
      int row = cid >> 3;
      int c   = (cid & 7) ^ (row & 7);
      gld_lds16(Bb + (size_t)(J0 + row) * KK + k0 + c * 8, sB + cid * 16);
    }
  };

  f32x4 acc[MF][NF] = {};

  stage(0, 0);
  for (int t = 0; t < NT; ++t) {
    const char* lA = smem + (t & 1) * SZ;
    const char* lB = lA + BM * 128;

    if (t + 1 < NT) { stage((t + 1) & 1, (t + 1) * 64); waitvm<L>(); }
    else            { waitvm<0>(); }
    __builtin_amdgcn_s_barrier();
    __builtin_amdgcn_sched_barrier(0);

    #pragma unroll
    for (int kk = 0; kk < 2; ++kk) {
      f16x8 af[MF], bf[NF];
      #pragma unroll
      for (int m = 0; m < MF; ++m) {
        int row = wm * (MF * 16) + m * 16 + lr;
        int cp  = (kk * 4 + hi) ^ (row & 7);
        af[m] = *(const f16x8*)(lA + ((row * 8 + cp) << 4));
      }
      #pragma unroll
      for (int n = 0; n < NF; ++n) {
        int row = wn * (NF * 16) + n * 16 + lr;
        int cp  = (kk * 4 + hi) ^ (row & 7);
        bf[n] = *(const f16x8*)(lB + ((row * 8 + cp) << 4));
      }
      __builtin_amdgcn_s_setprio(1);
      #pragma unroll
      for (int m = 0; m < MF; ++m)
        #pragma unroll
        for (int n = 0; n < NF; ++n)
          acc[m][n] = __builtin_amdgcn_mfma_f32_16x16x32_f16(af[m], bf[n], acc[m][n], 0, 0, 0);
      __builtin_amdgcn_s_setprio(0);
    }
    __builtin_amdgcn_sched_barrier(0);
    __builtin_amdgcn_s_barrier();   // protects buffer reuse by next stage()
  }

  // epilogue. C/D frag layout: col = lane&15, row = (lane>>4)*4 + reg.
  const int row0 = I0 + wm * (MF * 16);
  const int col0 = J0 + wn * (NF * 16);
  float bv[NF];
  if constexpr (EPI == 2) {
    #pragma unroll
    for (int n = 0; n < NF; ++n) bv[n] = bias[col0 + n * 16 + lr];
  }
  #pragma unroll
  for (int m = 0; m < MF; ++m) {
    #pragma unroll
    for (int i = 0; i < 4; ++i) {
      int r = row0 + m * 16 + (hi << 2) + i;
      #pragma unroll
      for (int n = 0; n < NF; ++n) {
        int c = col0 + n * 16 + lr;
        float v = acc[m][n][i];
        long off = (long)bz * sCb + (size_t)r * LDC + c;
        if constexpr (EPI == 0) {
          ((u16*)C)[off] = f2h(v * scale);
        } else if constexpr (EPI == 1) {
          ((u16*)C)[off] = f2h(v);
        } else {
          ((float*)C)[off] = v + bv[n];
        }
      }
    }
  }
}

// ---------------------------------------------------------------------------
// row softmax: scores [16384][1024] f16 -> prob f16. One wave per row.
// ---------------------------------------------------------------------------
__global__ __launch_bounds__(256) void softmax_kernel(
    const u16* __restrict__ scores, u16* __restrict__ prob) {
  const int lane = threadIdx.x & 63;
  const int wv   = threadIdx.x >> 6;
  const long row = (long)blockIdx.x * 4 + wv;
  const u16* src = scores + row * S_;

  u16x8 a0 = *(const u16x8*)&src[lane * 16];
  u16x8 a1 = *(const u16x8*)&src[lane * 16 + 8];
  float v[16];
  #pragma unroll
  for (int j = 0; j < 8; ++j) { v[j] = h2f(a0[j]); v[8 + j] = h2f(a1[j]); }

  float mx = -3.4e38f;
  #pragma unroll
  for (int j = 0; j < 16; ++j) mx = fmaxf(mx, v[j]);
  #pragma unroll
  for (int off = 32; off > 0; off >>= 1)
    mx = fmaxf(mx, __shfl_xor(mx, off));

  const float l2e = 1.4426950408889634f;
  float sum = 0.f;
  #pragma unroll
  for (int j = 0; j < 16; ++j) { v[j] = exp2f((v[j] - mx) * l2e); sum += v[j]; }
  #pragma unroll
  for (int off = 32; off > 0; off >>= 1)
    sum += __shfl_xor(sum, off);
  const float inv = 1.f / sum;

  u16x8 o0, o1;
  #pragma unroll
  for (int j = 0; j < 8; ++j) { o0[j] = f2h(v[j] * inv); o1[j] = f2h(v[8 + j] * inv); }
  *(u16x8*)&prob[row * S_ + lane * 16]     = o0;
  *(u16x8*)&prob[row * S_ + lane * 16 + 8] = o1;
}

// ---------------------------------------------------------------------------
extern "C" void kernel_launch(void* const* d_in, const int* in_sizes, int n_in,
                              void* d_out, int out_size, void* d_ws, size_t ws_size,
                              hipStream_t stream) {
  const float* data = (const float*)d_in[0];   // [16][1024][512]
  const float* W    = (const float*)d_in[1];   // [256][512]
  const float* bias = (const float*)d_in[2];   // [256]
  float* out = (float*)d_out;                  // [16][2048][256]
  char*  ws  = (char*)d_ws;

  const size_t MB = 1024 * 1024;
  u16* dataH  = (u16*)(ws);                    // 16 MB  [B][S][D] f16
  u16* Wh     = (u16*)(ws + 16 * MB);          // 256 KB [P][D] f16
  u16* scoresH= (u16*)(ws + 17 * MB);          // 32 MB  [B][S][S] f16
  u16* probH  = (u16*)(ws + 49 * MB);          // 32 MB  [B][S][S] f16
  u16* VWT    = (u16*)(ws + 81 * MB);          // 8 MB   [B][P][S] f16

  const float scale = 0.04419417382415922f;    // 1/sqrt(512)

  // big: BM=BN=256, 8 waves 2x4 (wave 128x64), LDS 128 KB
  constexpr int SMEM_BIG  = 2 * (256 + 256) * 128;
  // wide: BM=64, BN=256, 2 waves 1x2 (wave 64x128), LDS 80 KB
  constexpr int SMEM_WIDE = 2 * (64 + 256) * 128;

  auto* kG1 = (const void*)&gemm_pipe<0, 512,  256, 256, 8, 4, 2>;
  auto* kVW = (const void*)&gemm_pipe<1, 512,  64,  256, 2, 2, 1>;
  auto* kG2 = (const void*)&gemm_pipe<2, 1024, 64,  256, 2, 2, 1>;
  hipFuncSetAttribute(kG1, hipFuncAttributeMaxDynamicSharedMemorySize, SMEM_BIG);
  hipFuncSetAttribute(kVW, hipFuncAttributeMaxDynamicSharedMemorySize, SMEM_WIDE);
  hipFuncSetAttribute(kG2, hipFuncAttributeMaxDynamicSharedMemorySize, SMEM_WIDE);

  convert_f16_kernel<<<2048, 256, 0, stream>>>(data, dataH, (long)B_ * S_ * D_ / 4);
  convert_f16_kernel<<<64, 256, 0, stream>>>(W, Wh, (long)P_ * D_ / 4);

  // VWT[b] = Wh (256x512) @ dataH[b]^T -> [256][1024] f16
  gemm_pipe<1, 512, 64, 256, 2, 2, 1><<<dim3(4, 4, 16), 128, SMEM_WIDE, stream>>>(
      Wh, dataH, (void*)VWT, nullptr,
      0L, (long)S_ * D_, (long)P_ * S_, S_, 0.f);

  // scores[b] = scale * dataH[b] @ dataH[b]^T -> [1024][1024] f16
  gemm_pipe<0, 512, 256, 256, 8, 4, 2><<<dim3(4, 4, 16), 512, SMEM_BIG, stream>>>(
      dataH, dataH, (void*)scoresH, nullptr,
      (long)S_ * D_, (long)S_ * D_, (long)S_ * S_, S_, scale);

  softmax_kernel<<<4096, 256, 0, stream>>>(scoresH, probH);

  // out[b][:S] = prob[b] @ VWT[b]^T + bias -> f32; grid-y 16..31 zero the tail
  gemm_pipe<2, 1024, 64, 256, 2, 2, 1><<<dim3(1, 32, 16), 128, SMEM_WIDE, stream>>>(
      probH, VWT, (void*)out, bias,
      (long)S_ * S_, (long)P_ * S_, (long)MAXS_ * P_, P_, 0.f);
}